// Round 6
// baseline (176.648 us; speedup 1.0000x reference)
//
#include <hip/hip_runtime.h>
#include <stdint.h>

// Rule 110 CA, batch=32, width=16384, 64 iterations, zero boundaries each step.
// idx = L + 2C + 4R, lookup[k]=(110>>k)&1  ==>  new = (L | C) & ~(L & C & R).
//
// v5: DIAGNOSTIC ROUND - v4 kernel launched TWICE (idempotent stores).
//   Purpose: measure true kernel duration K via marginal cost, since the CA
//   dispatch never surfaces in the rocprof top-5 (harness poison-fills at
//   82-90us occupy all slots). Four structural rewrites (LDS-bounce, shfl,
//   8-deep bursts, nontemporal) all gave total = fill + ~56us invariant:
//   either the kernel is pinned at ~55us by an unknown invariant, or it is
//   ~25us (near the 136MB write floor) and ~30us is fixed harness overhead.
//   dur_us ~= old_total + K:  ~165-172 -> K~25 (roofline, revert next round);
//                             ~190-200 -> K~55 (real bottleneck, keep digging).
//   nt stores ensure launch #2 is not cache-warm-absorbed (true marginal K).

#define WIDTH 16384
#define BATCH 32
#define ITERS 64
#define TILE  1024
#define NTILE (WIDTH / TILE)   // 16
#define REP   4                // store-replicas per tile
#define SB    8                // steps batched per store burst

typedef int v4i __attribute__((ext_vector_type(4)));

__device__ __forceinline__ void nt_store4(int* p, uint32_t nib)
{
    v4i v;
    v.x = (int)(nib & 1u);
    v.y = (int)((nib >> 1) & 1u);
    v.z = (int)((nib >> 2) & 1u);
    v.w = (int)((nib >> 3) & 1u);
    __builtin_nontemporal_store(v, (v4i*)p);   // global_store_dwordx4 ... nt
}

__global__ __launch_bounds__(64) void ca_fused_kernel(
    const float* __restrict__ x, int* __restrict__ out)
{
    const int lane = threadIdx.x;          // 0..63
    const int tile = blockIdx.x;           // 0..15
    const int z    = blockIdx.y;           // 0..3  replica / store-quarter
    const int b    = blockIdx.z;           // 0..31
    const int s    = tile * TILE;          // output tile start cell

    // ---- pack initial state: lane owns working bits [lane*32, lane*32+32),
    //      i.e. global positions [s-64+lane*32, +32). Boundaries align to lanes.
    const int p0 = s - 64 + lane * 32;
    const bool valid = (p0 >= 0) && (p0 < WIDTH);
    const uint32_t vmask = valid ? 0xffffffffu : 0u;

    uint32_t c = 0;
    if (valid) {
        const float4* xv = (const float4*)(x + (size_t)b * WIDTH + p0);
        #pragma unroll
        for (int i = 0; i < 8; ++i) {
            float4 f = xv[i];
            c |= (uint32_t)(f.x >= 0.5f) << (i * 4 + 0);
            c |= (uint32_t)(f.y >= 0.5f) << (i * 4 + 1);
            c |= (uint32_t)(f.z >= 0.5f) << (i * 4 + 2);
            c |= (uint32_t)(f.w >= 0.5f) << (i * 4 + 3);
        }
    }

    // This replica stores tile cells [z*256 + lane*4, +4) each step.
    // Working bit of first stored cell = 64 + z*256 + lane*4
    //   -> source word = 2 + z*8 + (lane>>3), bit offset (lane&7)*4
    const int srcLane = 2 + z * 8 + (lane >> 3);
    const int sh4     = (lane & 7) * 4;

    int* outb = out + ((size_t)b * (ITERS + 1)) * WIDTH + s + z * 256 + lane * 4;

    for (int tb = 0; tb < ITERS / SB; ++tb) {
        uint32_t w[SB];   // fully unrolled -> registers (static indices only)

        // ---- compute phase: SB steps, snapshot store-words ----
        #pragma unroll
        for (int u = 0; u < SB; ++u) {
            w[u] = (uint32_t)__shfl((int)c, srcLane, 64);

            uint64_t A  = __ballot((c & 1u) != 0);         // LSBs of all lanes
            uint64_t Bm = __ballot((c >> 31) != 0);        // MSBs of all lanes
            uint32_t carryL = (uint32_t)(((Bm << 1) >> lane) & 1ull);
            uint32_t carryR = (uint32_t)(((A  >> 1) >> lane) & 1ull);

            uint32_t l = (c << 1) | carryL;
            uint32_t r = (c >> 1) | (carryR << 31);
            c = ((l | c) & ~(l & c & r)) & vmask;
        }

        // ---- store phase: SB back-to-back nontemporal dwordx4 bursts ----
        #pragma unroll
        for (int u = 0; u < SB; ++u) {
            nt_store4(outb + (size_t)u * WIDTH, w[u] >> sh4);
        }
        outb += SB * WIDTH;
    }

    // ---- final state (t = ITERS) store ----
    uint32_t wl = (uint32_t)__shfl((int)c, srcLane, 64);
    nt_store4(outb, wl >> sh4);
}

extern "C" void kernel_launch(void* const* d_in, const int* in_sizes, int n_in,
                              void* d_out, int out_size, void* d_ws, size_t ws_size,
                              hipStream_t stream)
{
    const float* x = (const float*)d_in[0];
    // d_in[1] = lookup table for rule 110 -- fixed by setup, baked into logic.
    (void)d_ws; (void)ws_size;

    dim3 grid(NTILE, REP, BATCH);   // 16 x 4 x 32 = 2048 single-wave blocks

    // DIAGNOSTIC: two identical, idempotent launches. Marginal cost of the
    // second = true kernel duration K (invisible in rocprof top-5 otherwise).
    ca_fused_kernel<<<grid, 64, 0, stream>>>(x, (int*)d_out);
    ca_fused_kernel<<<grid, 64, 0, stream>>>(x, (int*)d_out);
}

// Round 7
// 146.855 us; speedup vs baseline: 1.2029x; 1.2029x over previous
//
#include <hip/hip_runtime.h>
#include <stdint.h>

// Rule 110 CA, batch=32, width=16384, 64 iterations, zero boundaries each step.
// idx = L + 2C + 4R, lookup[k]=(110>>k)&1  ==>  new = (L | C) & ~(L & C & R).
//
// v6 (FINAL): single-launch v4. Measured facts from this session:
//   - true kernel duration K ~= 29.5us (double-launch marginal, round 6)
//     = 136 MB output / ~4.7 TB/s, ~75% of the harness fill's achieved BW.
//   - total dur_us = poison-fill (~82-90us, machine-state dependent)
//     + K (~29us) + ~28us fixed harness dispatch/gap overhead.
//   - four structural rewrites (LDS-bounce / shfl-only / 8-deep bursts /
//     nontemporal) all identical within noise -> kernel is at the write
//     floor; occupancy, MLP depth, and cache path each excluded by A/B.
//   Trapezoid: 2048-bit working state/wave, 64-cell halo absorbs 64 steps of
//   zero-boundary staleness; replica z of each (row,tile) stores quarter
//   [z*256, z*256+256) of the 1024-cell tile each step (1 shfl + 1 dwordx4).

#define WIDTH 16384
#define BATCH 32
#define ITERS 64
#define TILE  1024
#define NTILE (WIDTH / TILE)   // 16
#define REP   4                // store-replicas per tile
#define SB    8                // steps batched per store burst

typedef int v4i __attribute__((ext_vector_type(4)));

__device__ __forceinline__ void nt_store4(int* p, uint32_t nib)
{
    v4i v;
    v.x = (int)(nib & 1u);
    v.y = (int)((nib >> 1) & 1u);
    v.z = (int)((nib >> 2) & 1u);
    v.w = (int)((nib >> 3) & 1u);
    __builtin_nontemporal_store(v, (v4i*)p);   // global_store_dwordx4 ... nt
}

__global__ __launch_bounds__(64) void ca_fused_kernel(
    const float* __restrict__ x, int* __restrict__ out)
{
    const int lane = threadIdx.x;          // 0..63
    const int tile = blockIdx.x;           // 0..15
    const int z    = blockIdx.y;           // 0..3  replica / store-quarter
    const int b    = blockIdx.z;           // 0..31
    const int s    = tile * TILE;          // output tile start cell

    // ---- pack initial state: lane owns working bits [lane*32, lane*32+32),
    //      i.e. global positions [s-64+lane*32, +32). Boundaries align to lanes.
    const int p0 = s - 64 + lane * 32;
    const bool valid = (p0 >= 0) && (p0 < WIDTH);
    const uint32_t vmask = valid ? 0xffffffffu : 0u;

    uint32_t c = 0;
    if (valid) {
        const float4* xv = (const float4*)(x + (size_t)b * WIDTH + p0);
        #pragma unroll
        for (int i = 0; i < 8; ++i) {
            float4 f = xv[i];
            c |= (uint32_t)(f.x >= 0.5f) << (i * 4 + 0);
            c |= (uint32_t)(f.y >= 0.5f) << (i * 4 + 1);
            c |= (uint32_t)(f.z >= 0.5f) << (i * 4 + 2);
            c |= (uint32_t)(f.w >= 0.5f) << (i * 4 + 3);
        }
    }

    // This replica stores tile cells [z*256 + lane*4, +4) each step.
    // Working bit of first stored cell = 64 + z*256 + lane*4
    //   -> source word = 2 + z*8 + (lane>>3), bit offset (lane&7)*4
    const int srcLane = 2 + z * 8 + (lane >> 3);
    const int sh4     = (lane & 7) * 4;

    int* outb = out + ((size_t)b * (ITERS + 1)) * WIDTH + s + z * 256 + lane * 4;

    for (int tb = 0; tb < ITERS / SB; ++tb) {
        uint32_t w[SB];   // fully unrolled -> registers (static indices only)

        // ---- compute phase: SB steps, snapshot store-words ----
        #pragma unroll
        for (int u = 0; u < SB; ++u) {
            w[u] = (uint32_t)__shfl((int)c, srcLane, 64);

            uint64_t A  = __ballot((c & 1u) != 0);         // LSBs of all lanes
            uint64_t Bm = __ballot((c >> 31) != 0);        // MSBs of all lanes
            uint32_t carryL = (uint32_t)(((Bm << 1) >> lane) & 1ull);
            uint32_t carryR = (uint32_t)(((A  >> 1) >> lane) & 1ull);

            uint32_t l = (c << 1) | carryL;
            uint32_t r = (c >> 1) | (carryR << 31);
            c = ((l | c) & ~(l & c & r)) & vmask;
        }

        // ---- store phase: SB back-to-back nontemporal dwordx4 bursts ----
        #pragma unroll
        for (int u = 0; u < SB; ++u) {
            nt_store4(outb + (size_t)u * WIDTH, w[u] >> sh4);
        }
        outb += SB * WIDTH;
    }

    // ---- final state (t = ITERS) store ----
    uint32_t wl = (uint32_t)__shfl((int)c, srcLane, 64);
    nt_store4(outb, wl >> sh4);
}

extern "C" void kernel_launch(void* const* d_in, const int* in_sizes, int n_in,
                              void* d_out, int out_size, void* d_ws, size_t ws_size,
                              hipStream_t stream)
{
    const float* x = (const float*)d_in[0];
    // d_in[1] = lookup table for rule 110 -- fixed by setup, baked into logic.
    (void)d_ws; (void)ws_size;

    dim3 grid(NTILE, REP, BATCH);   // 16 x 4 x 32 = 2048 single-wave blocks
    ca_fused_kernel<<<grid, 64, 0, stream>>>(x, (int*)d_out);
}